// Round 1
// 246.985 us; speedup vs baseline: 1.0616x; 1.0616x over previous
//
#include <hip/hip_runtime.h>
#include <cstdint>
#include <cstddef>

// Causal self-attention, B=4 L=2048 D=1024 H=16 HD=64.
// I/O dtype: float32; internal compute bf16 MFMA.
// Round-11: flash v8 — 32x32x16 MFMA (2x FLOP per LDS byte vs 16x16x32),
// KVBLK=64, wave owns 32 q rows (block tile 128 q, pairs p/15-p -> uniform
// 34 steps). P stays in registers: cvt_pk_bf16 + v_permlane32_swap build PV
// A-frags (no Ps LDS buffer). K/V rows XOR-swizzled (src-side pre-swizzle
// for global_load_lds) to kill the row-major b128 bank conflicts.

typedef __attribute__((ext_vector_type(8))) __bf16 bf16x8;
typedef __attribute__((ext_vector_type(4))) __bf16 bf16x4;
typedef __attribute__((ext_vector_type(4))) float f32x4;
typedef __attribute__((ext_vector_type(16))) float f32x16;

__device__ __forceinline__ f32x4 mfma_bf16(bf16x8 a, bf16x8 b, f32x4 c) {
  return __builtin_amdgcn_mfma_f32_16x16x32_bf16(a, b, c, 0, 0, 0);
}

__device__ __forceinline__ f32x16 mfma32(bf16x8 a, bf16x8 b, f32x16 c) {
  return __builtin_amdgcn_mfma_f32_32x32x16_bf16(a, b, c, 0, 0, 0);
}

__device__ __forceinline__ unsigned cvtpk(float a, float b) {
  unsigned r;
  asm("v_cvt_pk_bf16_f32 %0, %1, %2" : "=v"(r) : "v"(a), "v"(b));
  return r;
}

__device__ __forceinline__ void async_copy16(const void* gsrc, void* ldsdst) {
  __builtin_amdgcn_global_load_lds(
      (const __attribute__((address_space(1))) void*)gsrc,
      (__attribute__((address_space(3))) void*)ldsdst, 16, 0, 0);
}

// ---------------- f32 -> bf16 elementwise (4 elems/thread) ------------------
__global__ __launch_bounds__(256) void f32_to_bf16(
    const float* __restrict__ in, __bf16* __restrict__ out) {
  const size_t i = ((size_t)blockIdx.x * 256 + threadIdx.x) * 4;
  const float4 v = *(const float4*)&in[i];
  bf16x4 o = {(__bf16)v.x, (__bf16)v.y, (__bf16)v.z, (__bf16)v.w};
  *(bf16x4*)&out[i] = o;
}

// ------------- f32 transpose + convert: out[c][r] = (bf16)in[r][c] ----------
__global__ __launch_bounds__(256) void transpose_f32_bf16(
    const float* __restrict__ in, __bf16* __restrict__ out, int R, int C) {
  __shared__ float tile[32][33];
  const int c0 = blockIdx.x * 32;
  const int r0 = blockIdx.y * 32;
  const int tx = threadIdx.x & 31;
  const int ty = threadIdx.x >> 5;  // 0..7
#pragma unroll
  for (int i = 0; i < 32; i += 8)
    tile[ty + i][tx] = in[(size_t)(r0 + ty + i) * C + c0 + tx];
  __syncthreads();
#pragma unroll
  for (int i = 0; i < 32; i += 8)
    out[(size_t)(c0 + ty + i) * R + r0 + tx] = (__bf16)tile[tx][ty + i];
}

// ---------------- GEMM core: 128x128 tile, BK=32, 4 waves, m97 staging ------
// A-frag: lane reads A[m=lane&15][k=quad*8+j]; B symmetric; C/D:
// col=lane&15, row=quad*4+reg.

// Final proj GEMM: C (f32) [M][N] = A[M][K] * BT[N][K]^T
__global__ __launch_bounds__(256) void gemm_bt_f32out(
    const __bf16* __restrict__ A, const __bf16* __restrict__ BT,
    float* __restrict__ C, int M, int N, int K) {
  __shared__ __bf16 As[128 * 32];
  __shared__ __bf16 Bs[128 * 32];
  const int tid = threadIdx.x;
  const int wave = tid >> 6;
  const int lane = tid & 63;
  const int n16 = lane & 15;
  const int quad = lane >> 4;
  const int m0 = blockIdx.x * 128;
  const int n0 = blockIdx.y * 128;
  const int wr = wave >> 1;
  const int wc = wave & 1;

  const f32x4 zero = {0.f, 0.f, 0.f, 0.f};
  f32x4 acc[4][4];
#pragma unroll
  for (int i = 0; i < 4; ++i)
#pragma unroll
    for (int j = 0; j < 4; ++j) acc[i][j] = zero;

  const int KT = K >> 5;
  for (int kt = 0; kt < KT; ++kt) {
    const int k0 = kt << 5;
#pragma unroll
    for (int r = 0; r < 2; ++r) {
      const int li = (r << 8) + tid;
      const int row = li >> 2;
      const int kp8 = (li & 3) << 3;
      const int lbase = ((r << 8) + (wave << 6)) << 3;
      async_copy16(&A[(size_t)(m0 + row) * K + k0 + kp8], &As[lbase]);
      async_copy16(&BT[(size_t)(n0 + row) * K + k0 + kp8], &Bs[lbase]);
    }
    __syncthreads();
    bf16x8 af[4], bf[4];
#pragma unroll
    for (int t = 0; t < 4; ++t) {
      af[t] = *(const bf16x8*)&As[(wr * 64 + t * 16 + n16) * 32 + quad * 8];
      bf[t] = *(const bf16x8*)&Bs[(wc * 64 + t * 16 + n16) * 32 + quad * 8];
    }
#pragma unroll
    for (int mt = 0; mt < 4; ++mt)
#pragma unroll
      for (int nt = 0; nt < 4; ++nt)
        acc[mt][nt] = mfma_bf16(af[mt], bf[nt], acc[mt][nt]);
    __syncthreads();
  }
#pragma unroll
  for (int mt = 0; mt < 4; ++mt) {
#pragma unroll
    for (int r = 0; r < 4; ++r) {
      const int m = m0 + wr * 64 + mt * 16 + quad * 4 + r;
#pragma unroll
      for (int nt = 0; nt < 4; ++nt) {
        const int n = n0 + wc * 64 + nt * 16 + n16;
        C[(size_t)m * N + n] = acc[mt][nt][r];
      }
    }
  }
}

// ---------------- QKV GEMM with fused reshape epilogue ----------------------
// Q scaled by 0.125*log2(e) so flash uses exp2 directly. All three outputs
// route their 64x64 wave tiles through a wave-private 4KB LDS transpose
// (XOR-swizzled chunks) for coalesced b128 stores.
__global__ __launch_bounds__(256) void gemm_qkv(
    const __bf16* __restrict__ A, const __bf16* __restrict__ BT,
    __bf16* __restrict__ Q, __bf16* __restrict__ Kh, __bf16* __restrict__ VT) {
  __shared__ __bf16 As[128 * 32];
  __shared__ __bf16 Bs[128 * 32];
  const int tid = threadIdx.x;
  const int wave = tid >> 6;
  const int lane = tid & 63;
  const int n16 = lane & 15;
  const int quad = lane >> 4;
  const int m0 = blockIdx.x * 128;
  const int n0 = blockIdx.y * 128;
  const int wr = wave >> 1;
  const int wc = wave & 1;
  const int K = 1024;

  const f32x4 zero = {0.f, 0.f, 0.f, 0.f};
  f32x4 acc[4][4];
#pragma unroll
  for (int i = 0; i < 4; ++i)
#pragma unroll
    for (int j = 0; j < 4; ++j) acc[i][j] = zero;

  for (int kt = 0; kt < 32; ++kt) {
    const int k0 = kt << 5;
#pragma unroll
    for (int r = 0; r < 2; ++r) {
      const int li = (r << 8) + tid;
      const int row = li >> 2;
      const int kp8 = (li & 3) << 3;
      const int lbase = ((r << 8) + (wave << 6)) << 3;
      async_copy16(&A[(size_t)(m0 + row) * K + k0 + kp8], &As[lbase]);
      async_copy16(&BT[(size_t)(n0 + row) * K + k0 + kp8], &Bs[lbase]);
    }
    __syncthreads();
    bf16x8 af[4], bf[4];
#pragma unroll
    for (int t = 0; t < 4; ++t) {
      af[t] = *(const bf16x8*)&As[(wr * 64 + t * 16 + n16) * 32 + quad * 8];
      bf[t] = *(const bf16x8*)&Bs[(wc * 64 + t * 16 + n16) * 32 + quad * 8];
    }
#pragma unroll
    for (int mt = 0; mt < 4; ++mt)
#pragma unroll
      for (int nt = 0; nt < 4; ++nt)
        acc[mt][nt] = mfma_bf16(af[mt], bf[nt], acc[mt][nt]);
    __syncthreads();
  }

  __syncthreads();  // all waves done with As/Bs K-loop reads
  const int b = m0 >> 11;  // whole block same batch (128 | 2048)
  __bf16* tw = (wave < 2 ? As : Bs) + (wave & 1) * 2048;  // 4KB / wave
  const int l0w = (m0 & 2047) + wr * 64;

  if (n0 < 2048) {
    // Q or K block: transpose 64x64 wave tile (rows l', cols hd) so stores
    // are b128 along hd. Two passes of 32 l-rows (4KB LDS each).
    const float QSCALE = 0.125f * 1.44269504089f;  // 1/sqrt(64)*log2(e)
    const bool isQ = (n0 < 1024);
    const int h = ((n0 & 1023) >> 6) + wc;
    __bf16* dst = isQ ? Q : Kh;
    const size_t base = ((size_t)(b * 16 + h) * 2048) * 64;
#pragma unroll
    for (int pass = 0; pass < 2; ++pass) {
#pragma unroll
      for (int mt = 2 * pass; mt < 2 * pass + 2; ++mt) {
#pragma unroll
        for (int nt = 0; nt < 4; ++nt)
#pragma unroll
          for (int r = 0; r < 4; ++r) {
            const int hd = nt * 16 + n16;
            const int mm = (mt & 1) * 16 + quad * 4 + r;
            const float v =
                isQ ? acc[mt][nt][r] * QSCALE : acc[mt][nt][r];
            tw[mm * 64 + (((hd >> 3) ^ (mm & 7)) << 3) + (hd & 7)] =
                (__bf16)v;
          }
      }
#pragma unroll
      for (int i = 0; i < 4; ++i) {
        const int c = lane + 64 * i;
        const int row = c >> 3;            // l' within pass, 0..31
        const int hd0 = (c & 7) << 3;
        const int phys = (c & 7) ^ (row & 7);
        const bf16x8 v = *(const bf16x8*)&tw[row * 64 + phys * 8];
        *(bf16x8*)&dst[base + (size_t)(l0w + pass * 32 + row) * 64 + hd0] = v;
      }
    }
  } else {
    // V block: transpose to T[hd][l], store b128 along l into VT[d][l].
    const int h = ((n0 - 2048) >> 6) + wc;
    const size_t bhead = (size_t)(b * 16 + h);
#pragma unroll
    for (int pass = 0; pass < 2; ++pass) {
#pragma unroll
      for (int nt = 2 * pass; nt < 2 * pass + 2; ++nt) {
#pragma unroll
        for (int mt = 0; mt < 4; ++mt)
#pragma unroll
          for (int r = 0; r < 4; ++r) {
            const int hdp = (nt & 1) * 16 + n16;
            const int mm = mt * 16 + quad * 4 + r;
            const int phys = (mm >> 3) ^ (hdp & 7);
            tw[hdp * 64 + phys * 8 + (mm & 7)] = (__bf16)acc[mt][nt][r];
          }
      }
#pragma unroll
      for (int i = 0; i < 4; ++i) {
        const int c = lane + 64 * i;
        const int row = c >> 3;
        const int phys = (c & 7) ^ (row & 7);
        const bf16x8 v = *(const bf16x8*)&tw[row * 64 + phys * 8];
        *(bf16x8*)&VT[(bhead * 64 + pass * 32 + row) * 2048 + l0w +
                      (c & 7) * 8] = v;
      }
    }
  }
}

// ---------------- flash attention v8 -----------------------------------------
// grid (64 bh, 8 p); block p does q-tiles p and 15-p (128 rows each; wave w
// owns rows w*32..+31) -> uniform 34 k-steps of 64 cols, DMA double-buffer,
// one barrier/step. S^T = mfma_32x32x16(K-frag, Q-frag): lane holds one
// q-column (q = lane&31), 16 k-rows per 32-k chunk. P->PV A-frags built
// in-register: cvt_pk_bf16 pairs + v_permlane32_swap (no P LDS round-trip).
__global__ __launch_bounds__(256, 2) void flash_attn(
    const __bf16* __restrict__ Q, const __bf16* __restrict__ Kh,
    const __bf16* __restrict__ VT, __bf16* __restrict__ Y) {
  __shared__ __bf16 Ks[2][64 * 64];  // [k-col][d], 8-chunk rows, phys=c^(row&7)
  __shared__ __bf16 Vs[2][64 * 64];  // [d][k-col], same swizzle
  const int bh = blockIdx.x;  // 0..63
  const int p = blockIdx.y;   // 0..7
  const int tid = threadIdx.x;
  const int wave = tid >> 6;
  const int lane = tid & 63;
  const int lrow = lane & 31;
  const int hi = lane >> 5;
  const int lswz = lane & 7;
  const __bf16* Qb = Q + (size_t)bh * 2048 * 64;
  const __bf16* Kb = Kh + (size_t)bh * 2048 * 64;
  const __bf16* Vb = VT + (size_t)bh * 64 * 2048;
  const int b = bh >> 4;
  const int h = bh & 15;
  const f32x16 zero16 = {0.f, 0.f, 0.f, 0.f, 0.f, 0.f, 0.f, 0.f,
                         0.f, 0.f, 0.f, 0.f, 0.f, 0.f, 0.f, 0.f};

  // staging: 2 chunks (16B) per thread per matrix per step; source address
  // pre-swizzled so linear LDS dest + swizzled read agree (rule 21).
  const int srow = tid >> 3;                            // 0..31
  const int sswz = ((tid & 7) ^ (srow & 7)) << 3;       // elem offset in row
  const size_t kg0 = (size_t)srow * 64 + sswz;
  const size_t kg1 = (size_t)(srow + 32) * 64 + sswz;   // (row+32)&7 == row&7
  const size_t vg0 = (size_t)srow * 2048 + sswz;
  const size_t vg1 = (size_t)(srow + 32) * 2048 + sswz;
  const int ldst0 = wave * 512;                         // wave-uniform bases
  const int ldst1 = 2048 + wave * 512;

#pragma unroll
  for (int tt = 0; tt < 2; ++tt) {
    const int t = tt ? 15 - p : p;
    const int q0w = t * 128 + wave * 32;
    const int myq = q0w + lrow;

    bf16x8 qf[4];
#pragma unroll
    for (int i = 0; i < 4; ++i)
      qf[i] = *(const bf16x8*)&Qb[(size_t)myq * 64 + i * 16 + hi * 8];

    f32x16 o0 = zero16, o1 = zero16;
    float lsum = 0.f;
    const int nsteps = 2 * (t + 1);

    __syncthreads();  // prior tile's readers of Ks/Vs done
    // prologue DMA into buf0
    async_copy16(&Kb[kg0], &Ks[0][ldst0]);
    async_copy16(&Kb[kg1], &Ks[0][ldst1]);
    async_copy16(&Vb[vg0], &Vs[0][ldst0]);
    async_copy16(&Vb[vg1], &Vs[0][ldst1]);

    for (int kt = 0; kt < nsteps; ++kt) {
      const int buf = kt & 1;
      const int c0 = kt << 6;
      __syncthreads();  // drains DMA for buf; prior step's LDS reads done
      if (kt + 1 < nsteps) {
        const int nb = buf ^ 1;
        const int cn = c0 + 64;
        async_copy16(&Kb[kg0 + (size_t)cn * 64], &Ks[nb][ldst0]);
        async_copy16(&Kb[kg1 + (size_t)cn * 64], &Ks[nb][ldst1]);
        async_copy16(&Vb[vg0 + cn], &Vs[nb][ldst0]);
        async_copy16(&Vb[vg1 + cn], &Vs[nb][ldst1]);
      }
      if (c0 > q0w + 31) continue;  // fully masked for this wave

      const __bf16* ks = Ks[buf];
      const __bf16* vs = Vs[buf];

      // S^T chunks: sc[ch] covers k = c0+ch*32+[(r&3)+8*(r>>2)+4*hi], q=lrow
      f32x16 sc[2];
#pragma unroll
      for (int ch = 0; ch < 2; ++ch) {
        sc[ch] = zero16;
#pragma unroll
        for (int i = 0; i < 4; ++i) {
          const bf16x8 kf = *(const bf16x8*)&ks[(ch * 32 + lrow) * 64 +
                                                (((2 * i + hi) ^ lswz) << 3)];
          sc[ch] = mfma32(kf, qf[i], sc[ch]);
        }
      }
      // exp2 (log2e folded into Q); mask only on the 1 diagonal step/wave
      if (c0 + 63 > q0w) {
#pragma unroll
        for (int ch = 0; ch < 2; ++ch)
#pragma unroll
          for (int r = 0; r < 16; ++r) {
            const int k = c0 + ch * 32 + (r & 3) + 8 * (r >> 2) + 4 * hi;
            float e = __builtin_amdgcn_exp2f(sc[ch][r]);
            e = (k <= myq) ? e : 0.f;
            sc[ch][r] = e;
            lsum += e;
          }
      } else {
#pragma unroll
        for (int ch = 0; ch < 2; ++ch)
#pragma unroll
          for (int r = 0; r < 16; ++r) {
            const float e = __builtin_amdgcn_exp2f(sc[ch][r]);
            sc[ch][r] = e;
            lsum += e;
          }
      }
      // PV: per 16-k chunk build P A-frag in-register (T12), 2 d-tiles
#pragma unroll
      for (int ch = 0; ch < 2; ++ch) {
#pragma unroll
        for (int kc = 0; kc < 2; ++kc) {
          unsigned c01 = cvtpk(sc[ch][kc * 8 + 0], sc[ch][kc * 8 + 1]);
          unsigned c23 = cvtpk(sc[ch][kc * 8 + 2], sc[ch][kc * 8 + 3]);
          unsigned c45 = cvtpk(sc[ch][kc * 8 + 4], sc[ch][kc * 8 + 5]);
          unsigned c67 = cvtpk(sc[ch][kc * 8 + 6], sc[ch][kc * 8 + 7]);
          asm("v_permlane32_swap_b32 %0, %1" : "+v"(c01), "+v"(c45));
          asm("v_permlane32_swap_b32 %0, %1" : "+v"(c23), "+v"(c67));
          union {
            unsigned u[4];
            bf16x8 v;
          } pu;
          pu.u[0] = c01;  // P[q=lrow][k = hi*8 + 0,1]
          pu.u[1] = c23;
          pu.u[2] = c45;
          pu.u[3] = c67;
          const int kch = ch * 4 + kc * 2 + hi;
          {
            const bf16x8 vf0 = *(const bf16x8*)&vs[(0 * 32 + lrow) * 64 +
                                                   ((kch ^ lswz) << 3)];
            o0 = mfma32(pu.v, vf0, o0);
            const bf16x8 vf1 = *(const bf16x8*)&vs[(1 * 32 + lrow) * 64 +
                                                   ((kch ^ lswz) << 3)];
            o1 = mfma32(pu.v, vf1, o1);
          }
        }
      }
    }

    // epilogue: lane's lsum covers q=lrow (its 32 of 64 k); partner lane^32
    // has the rest. O C-layout: col=d=lrow, row=q=(r&3)+8*(r>>2)+4*hi.
    lsum += __shfl_xor(lsum, 32);
    const float inv = 1.0f / lsum;
    float invr[16];
#pragma unroll
    for (int r = 0; r < 16; ++r)
      invr[r] = __shfl(inv, (r & 3) + 8 * (r >> 2) + 4 * hi);
#pragma unroll
    for (int r = 0; r < 16; ++r) {
      const int row = q0w + (r & 3) + 8 * (r >> 2) + 4 * hi;
      const size_t yb = (size_t)(b * 2048 + row) * 1024 + h * 64;
      Y[yb + lrow] = (__bf16)(o0[r] * invr[r]);
      Y[yb + 32 + lrow] = (__bf16)(o1[r] * invr[r]);
    }
  }
}

// ---------------- launch ------------------------------------------------------
extern "C" void kernel_launch(void* const* d_in, const int* in_sizes, int n_in,
                              void* d_out, int out_size, void* d_ws,
                              size_t ws_size, hipStream_t stream) {
  const float* x = (const float*)d_in[0];      // [4,2048,1024] f32
  const float* Wqkv = (const float*)d_in[1];   // [1024,3072] f32
  const float* Wproj = (const float*)d_in[2];  // [1024,1024] f32
  float* out = (float*)d_out;                  // [4,2048,1024] f32

  char* ws = (char*)d_ws;  // ~75 MB
  __bf16* xb = (__bf16*)ws;     ws += (size_t)8192 * 1024 * 2;
  __bf16* WqkvT = (__bf16*)ws;  ws += (size_t)3072 * 1024 * 2;
  __bf16* WprojT = (__bf16*)ws; ws += (size_t)1024 * 1024 * 2;
  __bf16* Qs = (__bf16*)ws;     ws += (size_t)64 * 2048 * 64 * 2;
  __bf16* Ks = (__bf16*)ws;     ws += (size_t)64 * 2048 * 64 * 2;
  __bf16* VTs = (__bf16*)ws;    ws += (size_t)64 * 64 * 2048 * 2;
  __bf16* attn = xb;  // xb is dead after gemm_qkv; reuse its space

  f32_to_bf16<<<8192, 256, 0, stream>>>(x, xb);
  transpose_f32_bf16<<<dim3(96, 32), 256, 0, stream>>>(Wqkv, WqkvT, 1024, 3072);
  transpose_f32_bf16<<<dim3(32, 32), 256, 0, stream>>>(Wproj, WprojT, 1024, 1024);
  gemm_qkv<<<dim3(64, 24), 256, 0, stream>>>(xb, WqkvT, Qs, Ks, VTs);
  flash_attn<<<dim3(64, 8), 256, 0, stream>>>(Qs, Ks, VTs, attn);
  gemm_bt_f32out<<<dim3(64, 8), 256, 0, stream>>>(attn, WprojT, out,
                                                  8192, 1024, 1024);
}